// Round 1
// baseline (617.952 us; speedup 1.0000x reference)
//
#include <hip/hip_runtime.h>
#include <math.h>

// Problem constants
constexpr int BB = 2048;     // batch
constexpr int CC = 129;      // channels
constexpr int TT = 200;      // time
constexpr int NPAIR = BB * CC;          // 264192
constexpr int PPB = 16;                 // pairs per block in kA
constexpr int NBIN = 30;                // bins k=1..30
constexpr int TSTR = 102;               // table row stride in float2 (16B-aligned rows, bank-spread)
constexpr int TABN = NBIN * TSTR;       // 3060 float2 entries

// d_ws layout (in floats)
constexpr int OFF_AVG = 8192;                    // tab occupies 30*102*2=6120 floats
constexpr int OFF_MX  = OFF_AVG + NPAIR;
constexpr int OFF_FT  = OFF_MX + NPAIR;          // NPAIR*4 floats

// ---------------------------------------------------------------------------
// Init: windowed DFT table. tab[r][t] = (w[t]*cos(2pi*(r+1)*t/100), w[t]*sin(...))
// Rows r=0..29 <-> bins k=1..30. Pad t=100..101 with zeros.
// ---------------------------------------------------------------------------
__global__ void kInit(float2* __restrict__ tab) {
    int i = blockIdx.x * 256 + threadIdx.x;
    if (i >= TABN) return;
    int r = i / TSTR, t = i % TSTR;
    float2 v = {0.f, 0.f};
    if (t < 100) {
        double th = (2.0 * M_PI / 100.0) * (double)t;
        double w  = 0.5 - 0.5 * cos(th);
        double a  = th * (double)(r + 1);
        v.x = (float)(w * cos(a));
        v.y = (float)(w * sin(a));
    }
    tab[i] = v;
}

// ---------------------------------------------------------------------------
// Kernel A: per (b,c) pair -> avg, max, Welch band features.
// Block = 256 threads, 16 pairs/block, 16 threads/pair.
// Thread j of pair p handles bins k1=1+j and k2=17+j (k2<=30), all 3 segments.
// Detrend handled analytically: re_1 += 25*mu_seg (FFT(hann)[k]=0 for k>=2).
// ---------------------------------------------------------------------------
__global__ __launch_bounds__(256, 4) void kA(const float* __restrict__ x,
                                             const float2* __restrict__ tabg,
                                             float* __restrict__ avg,
                                             float* __restrict__ mx,
                                             float* __restrict__ feat) {
    __shared__ __align__(16) float xs[PPB][TT];      // 12.8 KB
    __shared__ __align__(16) float2 tb[TABN];        // 24.48 KB
    __shared__ float mus[PPB][3];
    __shared__ float bsum[PPB][4];

    const int tid = threadIdx.x;
    const int blk = blockIdx.x;

    // stage table
    for (int i = tid; i < TABN; i += 256) tb[i] = tabg[i];
    // stage x (16 pairs * 200 floats = 800 float4, fully coalesced)
    {
        const float4* xg = (const float4*)(x + (size_t)blk * PPB * TT);
        float4* xs4 = (float4*)&xs[0][0];
        for (int i = tid; i < PPB * TT / 4; i += 256) xs4[i] = xg[i];
    }
    if (tid < PPB * 4) ((float*)bsum)[tid] = 0.f;
    __syncthreads();

    const int p = tid >> 4;
    const int j = tid & 15;
    const float* xp = &xs[p][0];

    // ---- stats: half-sums (4x50) + max, reduced across the 16-lane group ----
    {
        float h0 = 0.f, h1 = 0.f, h2 = 0.f, h3 = 0.f;
        float m = -3.4e38f;
        for (int t = j; t < TT; t += 16) {
            float v = xp[t];
            m = fmaxf(m, v);
            if (t < 50) h0 += v;
            else if (t < 100) h1 += v;
            else if (t < 150) h2 += v;
            else h3 += v;
        }
        for (int o = 8; o >= 1; o >>= 1) {
            h0 += __shfl_xor(h0, o, 64);
            h1 += __shfl_xor(h1, o, 64);
            h2 += __shfl_xor(h2, o, 64);
            h3 += __shfl_xor(h3, o, 64);
            m = fmaxf(m, __shfl_xor(m, o, 64));
        }
        if (j == 0) {
            int pair = blk * PPB + p;
            avg[pair] = (h0 + h1 + h2 + h3) * (1.f / 200.f);
            mx[pair] = m;
            mus[p][0] = (h0 + h1) * 0.01f;
            mus[p][1] = (h1 + h2) * 0.01f;
            mus[p][2] = (h2 + h3) * 0.01f;
        }
    }
    __syncthreads();

    // ---- direct DFT: 2 bins x 3 segs x (re,im) register tile ----
    const int k1 = 1 + j;                  // 1..16
    const int k2v = 17 + j;                // 17..32
    const bool has2 = (k2v <= NBIN);
    const int k2 = has2 ? k2v : 17;
    const float* t1 = (const float*)&tb[(k1 - 1) * TSTR];
    const float* t2 = (const float*)&tb[(k2 - 1) * TSTR];

    float r1[3] = {0.f, 0.f, 0.f}, i1[3] = {0.f, 0.f, 0.f};
    float r2[3] = {0.f, 0.f, 0.f}, i2[3] = {0.f, 0.f, 0.f};

    #pragma unroll 5
    for (int t0 = 0; t0 < 100; t0 += 4) {
        float4 xa = *(const float4*)(xp + t0);            // seg0 (16B aligned)
        float2 xb0 = *(const float2*)(xp + t0 + 50);      // seg1 (8B aligned)
        float2 xb1 = *(const float2*)(xp + t0 + 52);
        float4 xc = *(const float4*)(xp + t0 + 100);      // seg2 (16B aligned)
        float4 wa0 = *(const float4*)(t1 + 2 * t0);
        float4 wa1 = *(const float4*)(t1 + 2 * t0 + 4);
        float4 wb0 = *(const float4*)(t2 + 2 * t0);
        float4 wb1 = *(const float4*)(t2 + 2 * t0 + 4);

        float xv0[4] = {xa.x, xa.y, xa.z, xa.w};
        float xv1[4] = {xb0.x, xb0.y, xb1.x, xb1.y};
        float xv2[4] = {xc.x, xc.y, xc.z, xc.w};
        float c1[4] = {wa0.x, wa0.z, wa1.x, wa1.z};
        float s1[4] = {wa0.y, wa0.w, wa1.y, wa1.w};
        float c2[4] = {wb0.x, wb0.z, wb1.x, wb1.z};
        float s2[4] = {wb0.y, wb0.w, wb1.y, wb1.w};

        #pragma unroll
        for (int u = 0; u < 4; u++) {
            r1[0] += xv0[u] * c1[u];  i1[0] += xv0[u] * s1[u];
            r1[1] += xv1[u] * c1[u];  i1[1] += xv1[u] * s1[u];
            r1[2] += xv2[u] * c1[u];  i1[2] += xv2[u] * s1[u];
            r2[0] += xv0[u] * c2[u];  i2[0] += xv0[u] * s2[u];
            r2[1] += xv1[u] * c2[u];  i2[1] += xv1[u] * s2[u];
            r2[2] += xv2[u] * c2[u];  i2[2] += xv2[u] * s2[u];
        }
    }

    // detrend correction (only k=1): re += 25*mu_seg  (since FFT(win)[1] = -25)
    if (k1 == 1) {
        r1[0] += 25.f * mus[p][0];
        r1[1] += 25.f * mus[p][1];
        r1[2] += 25.f * mus[p][2];
    }

    float v1 = r1[0]*r1[0] + i1[0]*i1[0] + r1[1]*r1[1] + i1[1]*i1[1] + r1[2]*r1[2] + i1[2]*i1[2];
    float v2 = r2[0]*r2[0] + i2[0]*i2[0] + r2[1]*r2[1] + i2[1]*i2[1] + r2[2]*r2[2] + i2[2]*i2[2];

    // band accumulation (inclusive boundaries -> bins 4,8,13 hit two bands)
    if (k1 <= 4)             atomicAdd(&bsum[p][0], v1);
    if (k1 >= 4 && k1 <= 8)  atomicAdd(&bsum[p][1], v1);
    if (k1 >= 8 && k1 <= 13) atomicAdd(&bsum[p][2], v1);
    if (k1 >= 13)            atomicAdd(&bsum[p][3], v1);   // k1 <= 16
    if (has2)                atomicAdd(&bsum[p][3], v2);   // 17..30

    __syncthreads();

    if (tid < PPB * 4) {
        int pp = tid >> 2, bb = tid & 3;
        const float cnt[4] = {4.f, 5.f, 6.f, 18.f};
        // psd = (re^2+im^2)/(100*37.5) * 2, averaged over 3 segs, then band mean
        float scl = 2.f / (11250.f * cnt[bb]);
        feat[(size_t)(blk * PPB + pp) * 4 + bb] = bsum[pp][bb] * scl;
    }
}

// ---------------------------------------------------------------------------
// Kernel B: attention + MLP head. One block (128 threads) per batch row.
// ---------------------------------------------------------------------------
__global__ __launch_bounds__(128) void kB(const float* __restrict__ avg,
                                          const float* __restrict__ mx,
                                          const float* __restrict__ feat,
                                          const float* __restrict__ w_att1,
                                          const float* __restrict__ w_att2,
                                          const float* __restrict__ w_bb,
                                          const float* __restrict__ b_bb,
                                          const float* __restrict__ w_fe1,
                                          const float* __restrict__ b_fe1,
                                          const float* __restrict__ w_fe2,
                                          const float* __restrict__ b_fe2,
                                          const float* __restrict__ w_h1,
                                          const float* __restrict__ b_h1,
                                          const float* __restrict__ w_h2,
                                          const float* __restrict__ b_h2,
                                          const float* __restrict__ w_h3,
                                          const float* __restrict__ b_h3,
                                          float* __restrict__ out) {
    __shared__ float s_avg[CC], s_mx[CC], s_fq[CC * 4];
    __shared__ float s_t1[16], s_v[CC], s_h[128], s_f1[128], s_g1[128], s_g2[64];

    const int b = blockIdx.x;
    const int tid = threadIdx.x;

    for (int i = tid; i < CC; i += 128) { s_avg[i] = avg[b * CC + i]; s_mx[i] = mx[b * CC + i]; }
    for (int i = tid; i < CC * 4; i += 128) s_fq[i] = feat[(size_t)b * CC * 4 + i];
    __syncthreads();

    // att hidden: relu(avg@w1) + relu(mx@w1)
    if (tid < 16) {
        float a = 0.f, m = 0.f;
        for (int c = 0; c < CC; c++) {
            float w = w_att1[c * 16 + tid];
            a += s_avg[c] * w;
            m += s_mx[c] * w;
        }
        s_t1[tid] = fmaxf(a, 0.f) + fmaxf(m, 0.f);
    }
    __syncthreads();

    // att = sigmoid(hidden@w2); v = avg*att
    for (int c = tid; c < CC; c += 128) {
        float l = 0.f;
        for (int jj = 0; jj < 16; jj++) l += s_t1[jj] * w_att2[jj * CC + c];
        float att = 1.f / (1.f + expf(-l));
        s_v[c] = s_avg[c] * att;
    }
    __syncthreads();

    // time_feat = relu(v@w_bb + b_bb) -> s_h[0:64]
    if (tid < 64) {
        float acc = b_bb[tid];
        for (int c = 0; c < CC; c++) acc += s_v[c] * w_bb[c * 64 + tid];
        s_h[tid] = fmaxf(acc, 0.f);
    }
    // f1 = relu(fq@w_fe1 + b_fe1) — all 128 threads
    {
        float acc = b_fe1[tid];
        #pragma unroll 4
        for (int i = 0; i < CC * 4; i++) acc += s_fq[i] * w_fe1[i * 128 + tid];
        s_f1[tid] = fmaxf(acc, 0.f);
    }
    __syncthreads();

    // f2 = relu(f1@w_fe2 + b_fe2) -> s_h[64:128]
    if (tid < 64) {
        float acc = b_fe2[tid];
        #pragma unroll 4
        for (int i = 0; i < 128; i++) acc += s_f1[i] * w_fe2[i * 64 + tid];
        s_h[64 + tid] = fmaxf(acc, 0.f);
    }
    __syncthreads();

    // g1 = relu(h@w_h1 + b_h1)
    {
        float acc = b_h1[tid];
        #pragma unroll 4
        for (int i = 0; i < 128; i++) acc += s_h[i] * w_h1[i * 128 + tid];
        s_g1[tid] = fmaxf(acc, 0.f);
    }
    __syncthreads();

    // g2 = relu(g1@w_h2 + b_h2)
    if (tid < 64) {
        float acc = b_h2[tid];
        #pragma unroll 4
        for (int i = 0; i < 128; i++) acc += s_g1[i] * w_h2[i * 64 + tid];
        s_g2[tid] = fmaxf(acc, 0.f);
    }
    __syncthreads();

    // out = g2 . w_h3 + b_h3 (wave-64 reduction)
    if (tid < 64) {
        float pz = s_g2[tid] * w_h3[tid];
        for (int o = 32; o >= 1; o >>= 1) pz += __shfl_xor(pz, o, 64);
        if (tid == 0) out[b] = pz + b_h3[0];
    }
}

// ---------------------------------------------------------------------------
extern "C" void kernel_launch(void* const* d_in, const int* in_sizes, int n_in,
                              void* d_out, int out_size, void* d_ws, size_t ws_size,
                              hipStream_t stream) {
    const float* x      = (const float*)d_in[0];
    const float* w_att1 = (const float*)d_in[1];
    const float* w_att2 = (const float*)d_in[2];
    const float* w_bb   = (const float*)d_in[3];
    const float* b_bb   = (const float*)d_in[4];
    const float* w_fe1  = (const float*)d_in[5];
    const float* b_fe1  = (const float*)d_in[6];
    const float* w_fe2  = (const float*)d_in[7];
    const float* b_fe2  = (const float*)d_in[8];
    const float* w_h1   = (const float*)d_in[9];
    const float* b_h1   = (const float*)d_in[10];
    const float* w_h2   = (const float*)d_in[11];
    const float* b_h2   = (const float*)d_in[12];
    const float* w_h3   = (const float*)d_in[13];
    const float* b_h3   = (const float*)d_in[14];

    float* ws = (float*)d_ws;
    float2* tab = (float2*)ws;
    float* avg = ws + OFF_AVG;
    float* mxv = ws + OFF_MX;
    float* feat = ws + OFF_FT;

    kInit<<<(TABN + 255) / 256, 256, 0, stream>>>(tab);
    kA<<<NPAIR / PPB, 256, 0, stream>>>(x, (const float2*)tab, avg, mxv, feat);
    kB<<<BB, 128, 0, stream>>>(avg, mxv, feat,
                               w_att1, w_att2, w_bb, b_bb,
                               w_fe1, b_fe1, w_fe2, b_fe2,
                               w_h1, b_h1, w_h2, b_h2, w_h3, b_h3,
                               (float*)d_out);
}

// Round 2
// 494.038 us; speedup vs baseline: 1.2508x; 1.2508x over previous
//
#include <hip/hip_runtime.h>
#include <math.h>

// Problem constants
constexpr int BB = 2048;     // batch
constexpr int CC = 129;      // channels
constexpr int TT = 200;      // time
constexpr int NPAIR = BB * CC;          // 264192
constexpr int PPB = 64;                 // pairs per block in kA (lane = pair)
constexpr int XSTR = 201;               // x row stride in floats (odd -> 2-way LDS aliasing = free)

// d_ws layout (in floats)
constexpr int OFF_AVG = 8192;                    // tab occupies 30*100*2 = 6000 floats
constexpr int OFF_MX  = OFF_AVG + NPAIR;
constexpr int OFF_FT  = OFF_MX + NPAIR;          // NPAIR*4 floats

// ---------------------------------------------------------------------------
// Init: windowed DFT table, tab[k-1][t] = (w[t]*cos(2pi*k*t/100), w[t]*sin(...)).
// Integer phase reduction makes float trig exact enough (~1e-7 rel).
// ---------------------------------------------------------------------------
__global__ void kInit(float2* __restrict__ tab) {
    int i = blockIdx.x * 256 + threadIdx.x;
    if (i >= 3000) return;
    int r = i / 100, t = i % 100;
    int ph = ((r + 1) * t) % 100;                 // exact mod-100 reduction
    const float C = 0.06283185307179587f;         // 2*pi/100
    float w = 0.5f - 0.5f * cosf(C * (float)t);
    float ang = C * (float)ph;
    tab[i] = make_float2(w * cosf(ang), w * sinf(ang));
}

// ---------------------------------------------------------------------------
// Kernel A worker: one wave handles bins KB..KB+NB-1 for all 64 pairs.
// lane = pair. Table reads are wave-uniform (LDS broadcast, free).
// STATS wave also folds avg/max/segment-mean computation into the DFT loop.
// ---------------------------------------------------------------------------
template<int KB, int NB, bool STATS>
__device__ __forceinline__ void do_wave(const float* __restrict__ xp,
                                        const float* __restrict__ tbf,
                                        float* __restrict__ bs,
                                        int pair,
                                        float* __restrict__ avg,
                                        float* __restrict__ mxg) {
    const float* trow = tbf + (KB - 1) * 200;     // 200 floats per bin row
    float re[NB][3], im[NB][3];
    #pragma unroll
    for (int b = 0; b < NB; b++)
        #pragma unroll
        for (int s = 0; s < 3; s++) { re[b][s] = 0.f; im[b][s] = 0.f; }
    float h0 = 0.f, h1 = 0.f, h2 = 0.f, h3 = 0.f, m = -3.4e38f;

    auto run = [&](int t0, int t1, float& hA, float& hC) {
        for (int t = t0; t < t1; t += 2) {
            float a0 = xp[t],       a1 = xp[t + 1];
            float b0 = xp[t + 50],  b1 = xp[t + 51];
            float c0 = xp[t + 100], c1 = xp[t + 101];
            if (STATS) {
                hA += a0 + a1; hC += c0 + c1;
                m = fmaxf(m, fmaxf(fmaxf(a0, a1), fmaxf(c0, c1)));
            }
            #pragma unroll
            for (int b = 0; b < NB; b++) {
                float4 w = *(const float4*)(trow + b * 200 + 2 * t);  // broadcast
                re[b][0] += a0 * w.x; im[b][0] += a0 * w.y;
                re[b][0] += a1 * w.z; im[b][0] += a1 * w.w;
                re[b][1] += b0 * w.x; im[b][1] += b0 * w.y;
                re[b][1] += b1 * w.z; im[b][1] += b1 * w.w;
                re[b][2] += c0 * w.x; im[b][2] += c0 * w.y;
                re[b][2] += c1 * w.z; im[b][2] += c1 * w.w;
            }
        }
    };
    run(0, 50, h0, h2);     // a covers t 0..49 -> h0 ; c covers 100..149 -> h2
    run(50, 100, h1, h3);   // a covers 50..99  -> h1 ; c covers 150..199 -> h3

    if (STATS) {
        // segment means for detrend; FFT(hann)[1] = -25, zero for k>=2
        float mu0 = (h0 + h1) * 0.01f, mu1 = (h1 + h2) * 0.01f, mu2 = (h2 + h3) * 0.01f;
        re[0][0] += 25.f * mu0;   // bin k=1 lives in the STATS wave (KB==1)
        re[0][1] += 25.f * mu1;
        re[0][2] += 25.f * mu2;
        avg[pair] = (h0 + h1 + h2 + h3) * (1.f / 200.f);
        mxg[pair] = m;
    }

    float s0 = 0.f, s1 = 0.f, s2 = 0.f, s3 = 0.f;
    #pragma unroll
    for (int b = 0; b < NB; b++) {
        int k = KB + b;
        float v = re[b][0] * re[b][0] + im[b][0] * im[b][0]
                + re[b][1] * re[b][1] + im[b][1] * im[b][1]
                + re[b][2] * re[b][2] + im[b][2] * im[b][2];
        if (k >= 1  && k <= 4)  s0 += v;
        if (k >= 4  && k <= 8)  s1 += v;
        if (k >= 8  && k <= 13) s2 += v;
        if (k >= 13 && k <= 30) s3 += v;
    }
    if (KB <= 4)                       atomicAdd(&bs[0], s0);
    if (KB <= 8 && KB + NB - 1 >= 4)   atomicAdd(&bs[1], s1);
    if (KB <= 13 && KB + NB - 1 >= 8)  atomicAdd(&bs[2], s2);
    if (KB + NB - 1 >= 13)             atomicAdd(&bs[3], s3);
}

// ---------------------------------------------------------------------------
// Kernel A: 256 threads = 4 waves, 64 pairs/block, lane = pair.
// wave0: bins 1..6 + stats; wave1: 7..14; wave2: 15..22; wave3: 23..30.
// ---------------------------------------------------------------------------
__global__ __launch_bounds__(256, 2) void kA(const float* __restrict__ x,
                                             const float2* __restrict__ tabg,
                                             float* __restrict__ avg,
                                             float* __restrict__ mxg,
                                             float* __restrict__ feat) {
    __shared__ __align__(16) float xs[PPB * XSTR];   // 51456 B
    __shared__ __align__(16) float tbf[6000];        // 24000 B
    __shared__ float bsum[PPB][4];                   // 1024 B

    const int tid = threadIdx.x;
    const int blk = blockIdx.x;

    // stage table (contiguous float4)
    {
        const float4* tg = (const float4*)tabg;
        float4* td = (float4*)tbf;
        for (int i = tid; i < 1500; i += 256) td[i] = tg[i];
    }
    // stage x: 64 rows * 200 floats, written with stride-201 rows
    {
        const float4* xg = (const float4*)(x + (size_t)blk * PPB * TT);
        for (int i = tid; i < 3200; i += 256) {
            float4 v = xg[i];
            int p = i / 50, t4 = (i % 50) * 4;
            float* d = &xs[p * XSTR + t4];
            d[0] = v.x; d[1] = v.y; d[2] = v.z; d[3] = v.w;
        }
    }
    ((float*)bsum)[tid] = 0.f;
    __syncthreads();

    const int wv = tid >> 6, p = tid & 63;
    const float* xp = &xs[p * XSTR];
    float* bs = &bsum[p][0];
    const int pair = blk * PPB + p;

    if      (wv == 0) do_wave<1,  6, true >(xp, tbf, bs, pair, avg, mxg);
    else if (wv == 1) do_wave<7,  8, false>(xp, tbf, bs, pair, avg, mxg);
    else if (wv == 2) do_wave<15, 8, false>(xp, tbf, bs, pair, avg, mxg);
    else              do_wave<23, 8, false>(xp, tbf, bs, pair, avg, mxg);

    __syncthreads();
    {
        int pp = tid >> 2, bb = tid & 3;
        const float cnt[4] = {4.f, 5.f, 6.f, 18.f};
        // psd scale: /(100*37.5), *2 one-sided, /3 segs, / band count
        feat[(size_t)(blk * PPB + pp) * 4 + bb] = bsum[pp][bb] * (2.f / (11250.f * cnt[bb]));
    }
}

// ---------------------------------------------------------------------------
// Kernel B: attention + MLP head. 2 batch rows per block, 256 threads.
// ---------------------------------------------------------------------------
__global__ __launch_bounds__(256) void kB(const float* __restrict__ avg,
                                          const float* __restrict__ mxv,
                                          const float* __restrict__ feat,
                                          const float* __restrict__ w_att1,
                                          const float* __restrict__ w_att2,
                                          const float* __restrict__ w_bb,
                                          const float* __restrict__ b_bb,
                                          const float* __restrict__ w_fe1,
                                          const float* __restrict__ b_fe1,
                                          const float* __restrict__ w_fe2,
                                          const float* __restrict__ b_fe2,
                                          const float* __restrict__ w_h1,
                                          const float* __restrict__ b_h1,
                                          const float* __restrict__ w_h2,
                                          const float* __restrict__ b_h2,
                                          const float* __restrict__ w_h3,
                                          const float* __restrict__ b_h3,
                                          float* __restrict__ out) {
    __shared__ __align__(16) float s_avg[258], s_mx[258], s_fq[1032];
    __shared__ float s_t1[32];
    __shared__ __align__(16) float s_v[258], s_h[256], s_f1[256], s_g1[256], s_g2[128];

    const int b = blockIdx.x;      // handles batch rows 2b, 2b+1
    const int tid = threadIdx.x;

    for (int i = tid; i < 258; i += 256) { s_avg[i] = avg[b * 258 + i]; s_mx[i] = mxv[b * 258 + i]; }
    for (int i = tid; i < 1032; i += 256) s_fq[i] = feat[(size_t)b * 1032 + i];
    __syncthreads();

    // att hidden: relu(avg@w1) + relu(mx@w1), 2 rows x 16
    if (tid < 32) {
        int r = tid >> 4, h = tid & 15;
        const float* pa = &s_avg[r * 129];
        const float* pm = &s_mx[r * 129];
        float a = 0.f, m = 0.f;
        for (int c = 0; c < 129; c++) {
            float w = w_att1[c * 16 + h];
            a += pa[c] * w; m += pm[c] * w;
        }
        s_t1[r * 16 + h] = fmaxf(a, 0.f) + fmaxf(m, 0.f);
    }
    __syncthreads();

    // att = sigmoid(hidden@w2); v = avg*att
    for (int i = tid; i < 258; i += 256) {
        int r = i / 129, c = i - r * 129;
        const float* t1 = &s_t1[r * 16];
        float l = 0.f;
        #pragma unroll
        for (int j = 0; j < 16; j++) l += t1[j] * w_att2[j * 129 + c];
        s_v[i] = s_avg[i] / (1.f + expf(-l));
    }
    __syncthreads();

    // time_feat = relu(v@w_bb + b_bb) -> s_h[r][0:64]
    if (tid < 128) {
        int r = tid >> 6, o = tid & 63;
        const float* v = &s_v[r * 129];
        float acc = b_bb[o];
        for (int c = 0; c < 129; c++) acc += v[c] * w_bb[c * 64 + o];
        s_h[r * 128 + o] = fmaxf(acc, 0.f);
    }
    // f1 = relu(fq@w_fe1 + b_fe1): 2 rows x 128 outs (all 256 threads)
    {
        int r = tid >> 7, o = tid & 127;
        const float* fq = &s_fq[r * 516];
        float acc = b_fe1[o];
        for (int i = 0; i < 516; i += 4) {
            float4 q = *(const float4*)(fq + i);
            acc += q.x * w_fe1[(i    ) * 128 + o];
            acc += q.y * w_fe1[(i + 1) * 128 + o];
            acc += q.z * w_fe1[(i + 2) * 128 + o];
            acc += q.w * w_fe1[(i + 3) * 128 + o];
        }
        s_f1[r * 128 + o] = fmaxf(acc, 0.f);
    }
    __syncthreads();

    // f2 = relu(f1@w_fe2 + b_fe2) -> s_h[r][64:128]
    if (tid < 128) {
        int r = tid >> 6, o = tid & 63;
        const float* f = &s_f1[r * 128];
        float acc = b_fe2[o];
        for (int i = 0; i < 128; i += 4) {
            float4 q = *(const float4*)(f + i);
            acc += q.x * w_fe2[(i    ) * 64 + o];
            acc += q.y * w_fe2[(i + 1) * 64 + o];
            acc += q.z * w_fe2[(i + 2) * 64 + o];
            acc += q.w * w_fe2[(i + 3) * 64 + o];
        }
        s_h[r * 128 + 64 + o] = fmaxf(acc, 0.f);
    }
    __syncthreads();

    // g1 = relu(h@w_h1 + b_h1)
    {
        int r = tid >> 7, o = tid & 127;
        const float* hh = &s_h[r * 128];
        float acc = b_h1[o];
        for (int i = 0; i < 128; i += 4) {
            float4 q = *(const float4*)(hh + i);
            acc += q.x * w_h1[(i    ) * 128 + o];
            acc += q.y * w_h1[(i + 1) * 128 + o];
            acc += q.z * w_h1[(i + 2) * 128 + o];
            acc += q.w * w_h1[(i + 3) * 128 + o];
        }
        s_g1[r * 128 + o] = fmaxf(acc, 0.f);
    }
    __syncthreads();

    // g2 = relu(g1@w_h2 + b_h2)
    if (tid < 128) {
        int r = tid >> 6, o = tid & 63;
        const float* g = &s_g1[r * 128];
        float acc = b_h2[o];
        for (int i = 0; i < 128; i += 4) {
            float4 q = *(const float4*)(g + i);
            acc += q.x * w_h2[(i    ) * 64 + o];
            acc += q.y * w_h2[(i + 1) * 64 + o];
            acc += q.z * w_h2[(i + 2) * 64 + o];
            acc += q.w * w_h2[(i + 3) * 64 + o];
        }
        s_g2[r * 64 + o] = fmaxf(acc, 0.f);
    }
    __syncthreads();

    // out = g2 . w_h3 + b_h3 (one wave per row)
    if (tid < 128) {
        int r = tid >> 6, o = tid & 63;
        float pz = s_g2[r * 64 + o] * w_h3[o];
        for (int off = 32; off >= 1; off >>= 1) pz += __shfl_xor(pz, off, 64);
        if (o == 0) out[b * 2 + r] = pz + b_h3[0];
    }
}

// ---------------------------------------------------------------------------
extern "C" void kernel_launch(void* const* d_in, const int* in_sizes, int n_in,
                              void* d_out, int out_size, void* d_ws, size_t ws_size,
                              hipStream_t stream) {
    const float* x      = (const float*)d_in[0];
    const float* w_att1 = (const float*)d_in[1];
    const float* w_att2 = (const float*)d_in[2];
    const float* w_bb   = (const float*)d_in[3];
    const float* b_bb   = (const float*)d_in[4];
    const float* w_fe1  = (const float*)d_in[5];
    const float* b_fe1  = (const float*)d_in[6];
    const float* w_fe2  = (const float*)d_in[7];
    const float* b_fe2  = (const float*)d_in[8];
    const float* w_h1   = (const float*)d_in[9];
    const float* b_h1   = (const float*)d_in[10];
    const float* w_h2   = (const float*)d_in[11];
    const float* b_h2   = (const float*)d_in[12];
    const float* w_h3   = (const float*)d_in[13];
    const float* b_h3   = (const float*)d_in[14];

    float* ws = (float*)d_ws;
    float2* tab = (float2*)ws;
    float* avg = ws + OFF_AVG;
    float* mxv = ws + OFF_MX;
    float* feat = ws + OFF_FT;

    kInit<<<12, 256, 0, stream>>>(tab);
    kA<<<NPAIR / PPB, 256, 0, stream>>>(x, (const float2*)tab, avg, mxv, feat);
    kB<<<BB / 2, 256, 0, stream>>>(avg, mxv, feat,
                                   w_att1, w_att2, w_bb, b_bb,
                                   w_fe1, b_fe1, w_fe2, b_fe2,
                                   w_h1, b_h1, w_h2, b_h2, w_h3, b_h3,
                                   (float*)d_out);
}